// Round 8
// baseline (1936.462 us; speedup 1.0000x reference)
//
#include <hip/hip_runtime.h>
#include <cstdint>
#include <cstddef>

#define B_ 32
#define T_ 2048
#define D_ 128
#define U_ 128
#define G4_ 512
#define P1_ROWS 32
#define L2E_ 1.4426950408889634f

typedef _Float16 f16x8 __attribute__((ext_vector_type(8)));
typedef float f32x4 __attribute__((ext_vector_type(4)));

// LDS-visibility-only barrier (R5-proven): waits this wave's ds ops, syncs the
// block, does NOT drain vmcnt — out[] stores / Zx prefetches stay in flight.
__device__ __forceinline__ void lds_barrier() {
  __builtin_amdgcn_sched_barrier(0);
  asm volatile("s_waitcnt lgkmcnt(0)");
  __builtin_amdgcn_sched_barrier(0);
  __builtin_amdgcn_s_barrier();
  __builtin_amdgcn_sched_barrier(0);
}

// Phase 1: Zx[b][col][t] = s(col) * (bias[col] + sum_k x[b,t,k]*Wx[k][col])
// s(col) = -log2e for i,f,o gates; -2*log2e for g — folds the exp2 scale.
__global__ __launch_bounds__(512)
void zx_kernel(const float* __restrict__ x, const float* __restrict__ Wx,
               const float* __restrict__ bias, float* __restrict__ Zx,
               int tbase, int ct) {
  const int j = threadIdx.x;
  const int nt = ct / P1_ROWS;
  const int tblk = blockIdx.x % nt;
  const int b = blockIdx.x / nt;
  const int t0 = tblk * P1_ROWS;
  const float sj = ((j >> 7) == 2) ? (-2.f * L2E_) : (-L2E_);

  __shared__ float xsT[D_ * P1_ROWS];  // transposed: [k][r]

  const float* xp = x + ((size_t)b * T_ + tbase + t0) * D_;
  {
    int e = j * 8;
    int r = e >> 7;
    int k = e & 127;
    float4 v0 = *(const float4*)(xp + e);
    float4 v1 = *(const float4*)(xp + e + 4);
    xsT[(k + 0) * P1_ROWS + r] = v0.x;
    xsT[(k + 1) * P1_ROWS + r] = v0.y;
    xsT[(k + 2) * P1_ROWS + r] = v0.z;
    xsT[(k + 3) * P1_ROWS + r] = v0.w;
    xsT[(k + 4) * P1_ROWS + r] = v1.x;
    xsT[(k + 5) * P1_ROWS + r] = v1.y;
    xsT[(k + 6) * P1_ROWS + r] = v1.z;
    xsT[(k + 7) * P1_ROWS + r] = v1.w;
  }
  __syncthreads();

  const float bj = bias[j];
  float acc[P1_ROWS];
#pragma unroll
  for (int r = 0; r < P1_ROWS; ++r) acc[r] = bj;

  const float* wp = Wx + j;
  float w = wp[0];
#pragma unroll 2
  for (int k = 0; k < D_; ++k) {
    float wn = (k + 1 < D_) ? wp[(size_t)(k + 1) * G4_] : 0.f;
    const float4* xr = (const float4*)(xsT + k * P1_ROWS);
#pragma unroll
    for (int r4 = 0; r4 < P1_ROWS / 4; ++r4) {
      float4 xv = xr[r4];
      acc[4 * r4 + 0] += xv.x * w;
      acc[4 * r4 + 1] += xv.y * w;
      acc[4 * r4 + 2] += xv.z * w;
      acc[4 * r4 + 3] += xv.w * w;
    }
    w = wn;
  }

  float* zp = Zx + ((size_t)b * G4_ + j) * ct + t0;  // [b][col][t]
#pragma unroll
  for (int q = 0; q < P1_ROWS / 4; ++q)
    ((float4*)zp)[q] = make_float4(sj * acc[4 * q], sj * acc[4 * q + 1],
                                   sj * acc[4 * q + 2], sj * acc[4 * q + 3]);
}

// Phase 2: recurrence via f16 MFMA. 4 waves (256 thr) per batch: 1 wave/SIMD
// (no matrix-pipe contention), 16 LDS reads per CU-step (halved convoy).
// Wave w owns u in [32w, 32w+32): 8 col-tiles (4 gates x 2 u-subtiles) x 4
// k-tiles = 32 MFMA/step, depth-4 C-chains seeded from a persistent zero quad.
// Lane holds all 4 gates of u_lo=32w+l4 and u_hi=u_lo+16 -> lane-local cell.
// rg0 lanes write/store u_lo, rg1 write u_hi: one ds_write + one store.
__global__ __launch_bounds__(256, 1)
void lstm_kernel(const float* __restrict__ Zx, const float* __restrict__ Wh,
                 float* __restrict__ out, float* __restrict__ state,
                 int tbase, int ct, int first) {
  const int j = threadIdx.x;
  const int b = blockIdx.x;
  const int w = j >> 6;           // wave 0..3
  const int lane = j & 63;
  const int l4 = lane & 15;
  const int kg = lane >> 4;       // k-group (and row-group)
  const int u0 = 32 * w + l4;
  const int u1 = u0 + 16;
  const int uo = (kg == 1) ? u1 : u0;  // write target for lanes < 32

  // B fragments: bf[g][e][kt], col = g*128 + 32w + 16e + l4, k = kt*32+kg*8+el
  f16x8 bf[4][2][4];
#pragma unroll
  for (int g = 0; g < 4; ++g) {
    const float sg = (g == 2) ? (-2.f * L2E_) : (-L2E_);
#pragma unroll
    for (int e = 0; e < 2; ++e) {
#pragma unroll
      for (int kt = 0; kt < 4; ++kt) {
        f16x8 v;
#pragma unroll
        for (int el = 0; el < 8; ++el)
          v[el] = (_Float16)(sg * Wh[(size_t)(kt * 32 + kg * 8 + el) * G4_ +
                                     g * U_ + 32 * w + 16 * e + l4]);
        bf[g][e][kt] = v;
      }
    }
  }

  __shared__ alignas(16) _Float16 hbuf[2][U_];  // double-buffered h (f16)

  float c0s = 0.f, c1s = 0.f, hl0 = 0.f, hl1 = 0.f;
  if (!first) {
    hl0 = state[b * 2 * U_ + u0];
    hl1 = state[b * 2 * U_ + u1];
    c0s = state[b * 2 * U_ + U_ + u0];
    c1s = state[b * 2 * U_ + U_ + u1];
  }
  if (lane < 32) hbuf[0][uo] = (_Float16)((kg == 1) ? hl1 : hl0);
  __syncthreads();

  // 8 Zx streams per lane: (g, e) -> col = g*128 + 32w + 16e + l4; float2/2 steps
  const float2* zq[4][2];
#pragma unroll
  for (int g = 0; g < 4; ++g)
#pragma unroll
    for (int e = 0; e < 2; ++e)
      zq[g][e] = (const float2*)(Zx + ((size_t)b * G4_ + g * U_ + 32 * w +
                                       16 * e + l4) * ct);

  float2 zc[4][2], zn[4][2];
#pragma unroll
  for (int g = 0; g < 4; ++g)
#pragma unroll
    for (int e = 0; e < 2; ++e) zc[g][e] = zq[g][e][0];

  float* outp = out + ((size_t)tbase * B_ + b) * U_ + uo;
  const f32x4 zero4 = {0.f, 0.f, 0.f, 0.f};

  for (int tt = 0; tt < ct; tt += 2) {
    const bool more = (tt + 2 < ct);
    const int nq = (tt >> 1) + 1;
#pragma unroll
    for (int g = 0; g < 4; ++g)
#pragma unroll
      for (int e = 0; e < 2; ++e)
        zn[g][e] = more ? zq[g][e][nq] : make_float2(0.f, 0.f);

#pragma unroll
    for (int s = 0; s < 2; ++s) {
      const int t = tt + s;
      const int cur = t & 1;

      const f16x8* hp = (const f16x8*)hbuf[cur];
      f16x8 a0 = hp[0 * 4 + kg];
      f16x8 a1 = hp[1 * 4 + kg];
      f16x8 a2 = hp[2 * 4 + kg];
      f16x8 a3 = hp[3 * 4 + kg];

      f32x4 acc[4][2];
#pragma unroll
      for (int g = 0; g < 4; ++g)
#pragma unroll
        for (int e = 0; e < 2; ++e)
          acc[g][e] = __builtin_amdgcn_mfma_f32_16x16x32_f16(a0, bf[g][e][0], zero4, 0, 0, 0);
#pragma unroll
      for (int g = 0; g < 4; ++g)
#pragma unroll
        for (int e = 0; e < 2; ++e)
          acc[g][e] = __builtin_amdgcn_mfma_f32_16x16x32_f16(a1, bf[g][e][1], acc[g][e], 0, 0, 0);
#pragma unroll
      for (int g = 0; g < 4; ++g)
#pragma unroll
        for (int e = 0; e < 2; ++e)
          acc[g][e] = __builtin_amdgcn_mfma_f32_16x16x32_f16(a2, bf[g][e][2], acc[g][e], 0, 0, 0);
#pragma unroll
      for (int g = 0; g < 4; ++g)
#pragma unroll
        for (int e = 0; e < 2; ++e)
          acc[g][e] = __builtin_amdgcn_mfma_f32_16x16x32_f16(a3, bf[g][e][3], acc[g][e], 0, 0, 0);

      float act[4][2];
#pragma unroll
      for (int g = 0; g < 4; ++g) {
        const float mk = (g == 2) ? 2.f : 1.f;
        const float bk = (g == 2) ? -1.f : 0.f;
#pragma unroll
        for (int e = 0; e < 2; ++e) {
          float zi = (s == 0) ? zc[g][e].x : zc[g][e].y;
          float zs = acc[g][e][0] + zi;  // exp2-prescaled per gate
          act[g][e] = fmaf(__builtin_amdgcn_rcpf(1.f + __builtin_amdgcn_exp2f(zs)), mk, bk);
        }
      }

      c0s = fmaf(act[1][0], c0s, act[0][0] * act[2][0]);
      c1s = fmaf(act[1][1], c1s, act[0][1] * act[2][1]);
      float th0 = fmaf(
          __builtin_amdgcn_rcpf(1.f + __builtin_amdgcn_exp2f(-2.f * L2E_ * c0s)), 2.f, -1.f);
      float th1 = fmaf(
          __builtin_amdgcn_rcpf(1.f + __builtin_amdgcn_exp2f(-2.f * L2E_ * c1s)), 2.f, -1.f);
      hl0 = act[3][0] * th0;
      hl1 = act[3][1] * th1;

      if (lane < 32) {
        float hsel = (kg == 1) ? hl1 : hl0;
        outp[(size_t)t * B_ * U_] = hsel;
        hbuf[cur ^ 1][uo] = (_Float16)hsel;
      }
      lds_barrier();  // lgkmcnt(0) + s_barrier; vmem stays in flight
    }
#pragma unroll
    for (int g = 0; g < 4; ++g)
#pragma unroll
      for (int e = 0; e < 2; ++e) zc[g][e] = zn[g][e];
  }

  if (lane < 32) {
    state[b * 2 * U_ + uo] = (kg == 1) ? hl1 : hl0;
    state[b * 2 * U_ + U_ + uo] = (kg == 1) ? c1s : c0s;
  }
}

extern "C" void kernel_launch(void* const* d_in, const int* in_sizes, int n_in,
                              void* d_out, int out_size, void* d_ws, size_t ws_size,
                              hipStream_t stream) {
  const float* x = (const float*)d_in[0];
  const float* Wx = (const float*)d_in[1];
  const float* Wh = (const float*)d_in[2];
  const float* bias = (const float*)d_in[3];
  float* out = (float*)d_out;

  // ws layout: [0,32KB) = h/c carry state, rest = Zx chunk buffer
  float* state = (float*)d_ws;
  float* zx = (float*)((char*)d_ws + 32768);
  size_t avail = ws_size > 32768 ? ws_size - 32768 : 0;
  size_t per_t = (size_t)B_ * G4_ * sizeof(float);  // 64 KB per timestep
  long maxct = (long)(avail / per_t);
  int ct;
  if (maxct >= T_) ct = T_;
  else {
    ct = (int)((maxct / P1_ROWS) * P1_ROWS);
    if (ct < P1_ROWS) ct = P1_ROWS;
  }

  for (int tb = 0; tb < T_; tb += ct) {
    int cur = (T_ - tb < ct) ? (T_ - tb) : ct;
    zx_kernel<<<dim3(B_ * (cur / P1_ROWS)), 512, 0, stream>>>(x, Wx, bias, zx, tb, cur);
    lstm_kernel<<<dim3(B_), 256, 0, stream>>>(zx, Wh, out, state, tb, cur, tb == 0 ? 1 : 0);
  }
}

// Round 9
// 1382.796 us; speedup vs baseline: 1.4004x; 1.4004x over previous
//
#include <hip/hip_runtime.h>
#include <cstdint>
#include <cstddef>

#define B_ 32
#define T_ 2048
#define D_ 128
#define U_ 128
#define G4_ 512
#define P1_ROWS 32
#define L2E_ 1.4426950408889634f

typedef _Float16 f16x8 __attribute__((ext_vector_type(8)));
typedef float f32x4 __attribute__((ext_vector_type(4)));

// LDS-visibility-only barrier (R5-proven): waits this wave's ds ops, syncs the
// block, does NOT drain vmcnt — out[] stores / Zx prefetches stay in flight.
__device__ __forceinline__ void lds_barrier() {
  __builtin_amdgcn_sched_barrier(0);
  asm volatile("s_waitcnt lgkmcnt(0)");
  __builtin_amdgcn_sched_barrier(0);
  __builtin_amdgcn_s_barrier();
  __builtin_amdgcn_sched_barrier(0);
}

// Phase 1: Zx[b][col][t] = s(col) * (bias[col] + sum_k x[b,t,k]*Wx[k][col])
// s(col) = -log2e for i,f,o gates; -2*log2e for g — folds the exp2 scale.
__global__ __launch_bounds__(512)
void zx_kernel(const float* __restrict__ x, const float* __restrict__ Wx,
               const float* __restrict__ bias, float* __restrict__ Zx,
               int tbase, int ct) {
  const int j = threadIdx.x;
  const int nt = ct / P1_ROWS;
  const int tblk = blockIdx.x % nt;
  const int b = blockIdx.x / nt;
  const int t0 = tblk * P1_ROWS;
  const float sj = ((j >> 7) == 2) ? (-2.f * L2E_) : (-L2E_);

  __shared__ float xsT[D_ * P1_ROWS];  // transposed: [k][r]

  const float* xp = x + ((size_t)b * T_ + tbase + t0) * D_;
  {
    int e = j * 8;
    int r = e >> 7;
    int k = e & 127;
    float4 v0 = *(const float4*)(xp + e);
    float4 v1 = *(const float4*)(xp + e + 4);
    xsT[(k + 0) * P1_ROWS + r] = v0.x;
    xsT[(k + 1) * P1_ROWS + r] = v0.y;
    xsT[(k + 2) * P1_ROWS + r] = v0.z;
    xsT[(k + 3) * P1_ROWS + r] = v0.w;
    xsT[(k + 4) * P1_ROWS + r] = v1.x;
    xsT[(k + 5) * P1_ROWS + r] = v1.y;
    xsT[(k + 6) * P1_ROWS + r] = v1.z;
    xsT[(k + 7) * P1_ROWS + r] = v1.w;
  }
  __syncthreads();

  const float bj = bias[j];
  float acc[P1_ROWS];
#pragma unroll
  for (int r = 0; r < P1_ROWS; ++r) acc[r] = bj;

  const float* wp = Wx + j;
  float w = wp[0];
#pragma unroll 2
  for (int k = 0; k < D_; ++k) {
    float wn = (k + 1 < D_) ? wp[(size_t)(k + 1) * G4_] : 0.f;
    const float4* xr = (const float4*)(xsT + k * P1_ROWS);
#pragma unroll
    for (int r4 = 0; r4 < P1_ROWS / 4; ++r4) {
      float4 xv = xr[r4];
      acc[4 * r4 + 0] += xv.x * w;
      acc[4 * r4 + 1] += xv.y * w;
      acc[4 * r4 + 2] += xv.z * w;
      acc[4 * r4 + 3] += xv.w * w;
    }
    w = wn;
  }

  float* zp = Zx + ((size_t)b * G4_ + j) * ct + t0;  // [b][col][t]
#pragma unroll
  for (int q = 0; q < P1_ROWS / 4; ++q)
    ((float4*)zp)[q] = make_float4(sj * acc[4 * q], sj * acc[4 * q + 1],
                                   sj * acc[4 * q + 2], sj * acc[4 * q + 3]);
}

// Phase 2: recurrence via f16 MFMA. 8 waves per batch (R5 skeleton).
// Wave w owns u in [16w,16w+16); 4 gate N-tiles; A = broadcast h.
// Zero-seeded depth-2 K-chains (kt{0,1} / kt{2,3}) — no acc-init movs,
// 64-cy dep latency. exp2-folded activations. Lane-local cell update.
__global__ __launch_bounds__(512)
void lstm_kernel(const float* __restrict__ Zx, const float* __restrict__ Wh,
                 float* __restrict__ out, float* __restrict__ state,
                 int tbase, int ct, int first) {
  const int j = threadIdx.x;
  const int b = blockIdx.x;
  const int w = j >> 6;
  const int lane = j & 63;
  const int l4 = lane & 15;
  const int kg = lane >> 4;       // k-group 0..3
  const int u = w * 16 + l4;

  // B fragments: Wh'[k][col], col = g*128+u, k = kt*32 + kg*8 + e, prescaled
  f16x8 bf[4][4];
#pragma unroll
  for (int g = 0; g < 4; ++g) {
    const float sg = (g == 2) ? (-2.f * L2E_) : (-L2E_);
#pragma unroll
    for (int kt = 0; kt < 4; ++kt) {
      f16x8 v;
#pragma unroll
      for (int e = 0; e < 8; ++e)
        v[e] = (_Float16)(sg * Wh[(size_t)(kt * 32 + kg * 8 + e) * G4_ + g * U_ + u]);
      bf[g][kt] = v;
    }
  }

  __shared__ alignas(16) _Float16 hbuf[2][U_];  // double-buffered h (f16)

  float c_state = 0.f, h0 = 0.f;
  if (!first) {
    h0 = state[b * 2 * U_ + u];
    c_state = state[b * 2 * U_ + U_ + u];
  }
  if (kg == 0) hbuf[0][u] = (_Float16)h0;
  __syncthreads();

  const float4* zq0 = (const float4*)(Zx + ((size_t)b * G4_ + 0 * U_ + u) * ct);
  const float4* zq1 = (const float4*)(Zx + ((size_t)b * G4_ + 1 * U_ + u) * ct);
  const float4* zq2 = (const float4*)(Zx + ((size_t)b * G4_ + 2 * U_ + u) * ct);
  const float4* zq3 = (const float4*)(Zx + ((size_t)b * G4_ + 3 * U_ + u) * ct);

  float4 zc0 = zq0[0], zc1 = zq1[0], zc2 = zq2[0], zc3 = zq3[0];
  float hlast = h0;
  float* outp = out + ((size_t)tbase * B_ + b) * U_ + u;

  const f32x4 zero4 = {0.f, 0.f, 0.f, 0.f};

  for (int tt = 0; tt < ct; tt += 4) {
    float4 zn0, zn1, zn2, zn3;
    if (tt + 4 < ct) {
      const int nq = (tt >> 2) + 1;
      zn0 = zq0[nq]; zn1 = zq1[nq]; zn2 = zq2[nq]; zn3 = zq3[nq];
    } else {
      zn0 = zn1 = zn2 = zn3 = make_float4(0.f, 0.f, 0.f, 0.f);
    }
#pragma unroll
    for (int s = 0; s < 4; ++s) {
      const int t = tt + s;
      const int cur = t & 1;
      const float zi0 = (s == 0) ? zc0.x : (s == 1) ? zc0.y : (s == 2) ? zc0.z : zc0.w;
      const float zi1 = (s == 0) ? zc1.x : (s == 1) ? zc1.y : (s == 2) ? zc1.z : zc1.w;
      const float zi2 = (s == 0) ? zc2.x : (s == 1) ? zc2.y : (s == 2) ? zc2.z : zc2.w;
      const float zi3 = (s == 0) ? zc3.x : (s == 1) ? zc3.y : (s == 2) ? zc3.z : zc3.w;

      // A-frags: broadcast h slice per k-group (16B per kt)
      const f16x8* hp = (const f16x8*)hbuf[cur];
      f16x8 a0 = hp[0 * 4 + kg];
      f16x8 a2 = hp[2 * 4 + kg];
      f16x8 a1 = hp[1 * 4 + kg];
      f16x8 a3 = hp[3 * 4 + kg];

      // zero-seeded depth-2 chains: accA over kt{0,1}, accB over kt{2,3}
      f32x4 aA0 = __builtin_amdgcn_mfma_f32_16x16x32_f16(a0, bf[0][0], zero4, 0, 0, 0);
      f32x4 aA1 = __builtin_amdgcn_mfma_f32_16x16x32_f16(a0, bf[1][0], zero4, 0, 0, 0);
      f32x4 aA2 = __builtin_amdgcn_mfma_f32_16x16x32_f16(a0, bf[2][0], zero4, 0, 0, 0);
      f32x4 aA3 = __builtin_amdgcn_mfma_f32_16x16x32_f16(a0, bf[3][0], zero4, 0, 0, 0);
      f32x4 aB0 = __builtin_amdgcn_mfma_f32_16x16x32_f16(a2, bf[0][2], zero4, 0, 0, 0);
      f32x4 aB1 = __builtin_amdgcn_mfma_f32_16x16x32_f16(a2, bf[1][2], zero4, 0, 0, 0);
      f32x4 aB2 = __builtin_amdgcn_mfma_f32_16x16x32_f16(a2, bf[2][2], zero4, 0, 0, 0);
      f32x4 aB3 = __builtin_amdgcn_mfma_f32_16x16x32_f16(a2, bf[3][2], zero4, 0, 0, 0);
      aA0 = __builtin_amdgcn_mfma_f32_16x16x32_f16(a1, bf[0][1], aA0, 0, 0, 0);
      aA1 = __builtin_amdgcn_mfma_f32_16x16x32_f16(a1, bf[1][1], aA1, 0, 0, 0);
      aA2 = __builtin_amdgcn_mfma_f32_16x16x32_f16(a1, bf[2][1], aA2, 0, 0, 0);
      aA3 = __builtin_amdgcn_mfma_f32_16x16x32_f16(a1, bf[3][1], aA3, 0, 0, 0);
      aB0 = __builtin_amdgcn_mfma_f32_16x16x32_f16(a3, bf[0][3], aB0, 0, 0, 0);
      aB1 = __builtin_amdgcn_mfma_f32_16x16x32_f16(a3, bf[1][3], aB1, 0, 0, 0);
      aB2 = __builtin_amdgcn_mfma_f32_16x16x32_f16(a3, bf[2][3], aB2, 0, 0, 0);
      aB3 = __builtin_amdgcn_mfma_f32_16x16x32_f16(a3, bf[3][3], aB3, 0, 0, 0);

      // z' = s_g*z: exp2-prescaled per gate
      float zs0 = (aA0[0] + aB0[0]) + zi0;
      float zs1 = (aA1[0] + aB1[0]) + zi1;
      float zs2 = (aA2[0] + aB2[0]) + zi2;
      float zs3 = (aA3[0] + aB3[0]) + zi3;

      float i_ = __builtin_amdgcn_rcpf(1.f + __builtin_amdgcn_exp2f(zs0));
      float f_ = __builtin_amdgcn_rcpf(1.f + __builtin_amdgcn_exp2f(zs1));
      float g_ = fmaf(__builtin_amdgcn_rcpf(1.f + __builtin_amdgcn_exp2f(zs2)), 2.f, -1.f);
      float o_ = __builtin_amdgcn_rcpf(1.f + __builtin_amdgcn_exp2f(zs3));

      c_state = fmaf(f_, c_state, i_ * g_);
      float tc = fmaf(
          __builtin_amdgcn_rcpf(1.f + __builtin_amdgcn_exp2f(-2.f * L2E_ * c_state)),
          2.f, -1.f);
      float hn = o_ * tc;
      hlast = hn;

      if (kg == 0) {
        outp[(size_t)t * B_ * U_] = hn;
        hbuf[cur ^ 1][u] = (_Float16)hn;
      }
      lds_barrier();  // lgkmcnt(0) + s_barrier; vmem stays in flight
    }
    zc0 = zn0; zc1 = zn1; zc2 = zn2; zc3 = zn3;
  }

  if (kg == 0) {
    state[b * 2 * U_ + u] = hlast;
    state[b * 2 * U_ + U_ + u] = c_state;
  }
}

extern "C" void kernel_launch(void* const* d_in, const int* in_sizes, int n_in,
                              void* d_out, int out_size, void* d_ws, size_t ws_size,
                              hipStream_t stream) {
  const float* x = (const float*)d_in[0];
  const float* Wx = (const float*)d_in[1];
  const float* Wh = (const float*)d_in[2];
  const float* bias = (const float*)d_in[3];
  float* out = (float*)d_out;

  // ws layout: [0,32KB) = h/c carry state, rest = Zx chunk buffer
  float* state = (float*)d_ws;
  float* zx = (float*)((char*)d_ws + 32768);
  size_t avail = ws_size > 32768 ? ws_size - 32768 : 0;
  size_t per_t = (size_t)B_ * G4_ * sizeof(float);  // 64 KB per timestep
  long maxct = (long)(avail / per_t);
  int ct;
  if (maxct >= T_) ct = T_;
  else {
    ct = (int)((maxct / P1_ROWS) * P1_ROWS);
    if (ct < P1_ROWS) ct = P1_ROWS;
  }

  for (int tb = 0; tb < T_; tb += ct) {
    int cur = (T_ - tb < ct) ? (T_ - tb) : ct;
    zx_kernel<<<dim3(B_ * (cur / P1_ROWS)), 512, 0, stream>>>(x, Wx, bias, zx, tb, cur);
    lstm_kernel<<<dim3(B_), 512, 0, stream>>>(zx, Wh, out, state, tb, cur, tb == 0 ? 1 : 0);
  }
}